// Round 1
// baseline (434.117 us; speedup 1.0000x reference)
//
#include <hip/hip_runtime.h>
#include <cstdint>
#include <cstddef>

#define ALPHA 0.2f
#define NEG_INF -1e30f

constexpr int B = 4, N = 512, IN_F = 256, E_F = 64, OUT_F = 256;

// ---------------------------------------------------------------------------
// K1c: w1a3[e] = sum_o W1[e][o] * a3[o],  W1 is (64,256), a3 = a[512:768]
// ---------------------------------------------------------------------------
__global__ __launch_bounds__(256) void k_w1a3(const float* __restrict__ W1,
                                              const float* __restrict__ a,
                                              float* __restrict__ w1a3) {
    int tid = threadIdx.x;      // 256 threads: 4 threads per output e
    int e = tid >> 2;
    int part = tid & 3;
    const float* row = W1 + (size_t)e * OUT_F;
    float s = 0.f;
    int o0 = part * 64;
    for (int o = o0; o < o0 + 64; ++o)
        s += row[o] * a[2 * OUT_F + o];
    s += __shfl_xor(s, 1);
    s += __shfl_xor(s, 2);
    if (part == 0) w1a3[e] = s;
}

// ---------------------------------------------------------------------------
// K1a: h = x @ W  (rows = b*N+n), fused s_i = h.a1, s_j = h.a2
// 8 rows per block, 256 threads (one per output col)
// ---------------------------------------------------------------------------
__global__ __launch_bounds__(256) void k_h(const float* __restrict__ x,
                                           const float* __restrict__ W,
                                           const float* __restrict__ a,
                                           float* __restrict__ h,
                                           float* __restrict__ s_i,
                                           float* __restrict__ s_j) {
    constexpr int ROWS = 8;
    int row0 = blockIdx.x * ROWS;
    int o = threadIdx.x;
    __shared__ float xs[ROWS][IN_F];          // 8 KB
    #pragma unroll
    for (int r = 0; r < ROWS; ++r)
        xs[r][o] = x[(size_t)(row0 + r) * IN_F + o];
    __syncthreads();

    float acc[ROWS];
    #pragma unroll
    for (int r = 0; r < ROWS; ++r) acc[r] = 0.f;

    for (int k = 0; k < IN_F; k += 4) {
        float w0 = W[(size_t)(k + 0) * OUT_F + o];
        float w1 = W[(size_t)(k + 1) * OUT_F + o];
        float w2 = W[(size_t)(k + 2) * OUT_F + o];
        float w3 = W[(size_t)(k + 3) * OUT_F + o];
        #pragma unroll
        for (int r = 0; r < ROWS; ++r) {
            float4 xv = *(const float4*)&xs[r][k];
            acc[r] = fmaf(xv.x, w0, acc[r]);
            acc[r] = fmaf(xv.y, w1, acc[r]);
            acc[r] = fmaf(xv.z, w2, acc[r]);
            acc[r] = fmaf(xv.w, w3, acc[r]);
        }
    }

    float a1v = a[o];
    float a2v = a[OUT_F + o];
    __shared__ float p1s[4][ROWS], p2s[4][ROWS];
    int lane = o & 63, wv = o >> 6;
    #pragma unroll
    for (int r = 0; r < ROWS; ++r) {
        h[(size_t)(row0 + r) * OUT_F + o] = acc[r];
        float p1 = acc[r] * a1v;
        float p2 = acc[r] * a2v;
        #pragma unroll
        for (int off = 32; off; off >>= 1) {
            p1 += __shfl_xor(p1, off);
            p2 += __shfl_xor(p2, off);
        }
        if (lane == 0) { p1s[wv][r] = p1; p2s[wv][r] = p2; }
    }
    __syncthreads();
    if (o < ROWS) {
        s_i[row0 + o] = p1s[0][o] + p1s[1][o] + p1s[2][o] + p1s[3][o];
    } else if (o < 2 * ROWS) {
        int r = o - ROWS;
        s_j[row0 + r] = p2s[0][r] + p2s[1][r] + p2s[2][r] + p2s[3][r];
    }
}

// ---------------------------------------------------------------------------
// K2: per (b,i) row: s_e = edge.w1a3, e = leakyrelu(s_i+s_j+s_e), mask by adj,
//     softmax over j, write attention row. One block per (b,i).
//     Edge read pattern: 16 lanes x float4 cover one j (64 floats); each wave
//     does 4 consecutive j per iteration -> 1 KB contiguous per wave-load.
// ---------------------------------------------------------------------------
__global__ __launch_bounds__(256) void k_att(const float* __restrict__ edge,
                                             const float* __restrict__ adj,
                                             const float* __restrict__ s_i,
                                             const float* __restrict__ s_j,
                                             const float* __restrict__ w1a3,
                                             float* __restrict__ att) {
    int bi = blockIdx.x;            // b*N + i
    int b = bi >> 9;                // N = 512
    int tid = threadIdx.x;          // 256
    int lane = tid & 63, wv = tid >> 6;

    __shared__ float w1a3s[E_F];
    __shared__ float sjs[N];
    __shared__ float adjs[N];
    __shared__ float evals[N];
    __shared__ float redm[4], reds[4];

    if (tid < E_F) w1a3s[tid] = w1a3[tid];
    sjs[tid]        = s_j[b * N + tid];
    sjs[tid + 256]  = s_j[b * N + tid + 256];
    adjs[tid]       = adj[(size_t)bi * N + tid];
    adjs[tid + 256] = adj[(size_t)bi * N + tid + 256];
    float si = s_i[bi];
    __syncthreads();

    int jsub = lane >> 4;           // 0..3
    int eo = (lane & 15) * 4;       // element offset within the 64-dot
    float4 wv4 = *(const float4*)&w1a3s[eo];
    const float* ebase = edge + (size_t)bi * N * E_F;

    for (int it = 0; it < N / 16; ++it) {
        int j = it * 16 + wv * 4 + jsub;
        float4 ev = *(const float4*)(ebase + (size_t)j * E_F + eo);
        float p = ev.x * wv4.x + ev.y * wv4.y + ev.z * wv4.z + ev.w * wv4.w;
        p += __shfl_xor(p, 1);
        p += __shfl_xor(p, 2);
        p += __shfl_xor(p, 4);
        p += __shfl_xor(p, 8);
        if ((lane & 15) == 0) {
            float v = si + sjs[j] + p;
            v = v > 0.f ? v : ALPHA * v;
            evals[j] = (adjs[j] > 0.f) ? v : NEG_INF;
        }
    }
    __syncthreads();

    // masked softmax over evals[0..511]
    float v0 = evals[tid], v1 = evals[tid + 256];
    float m = fmaxf(v0, v1);
    #pragma unroll
    for (int off = 32; off; off >>= 1) m = fmaxf(m, __shfl_xor(m, off));
    if (lane == 0) redm[wv] = m;
    __syncthreads();
    m = fmaxf(fmaxf(redm[0], redm[1]), fmaxf(redm[2], redm[3]));

    float e0 = __expf(v0 - m);
    float e1 = __expf(v1 - m);
    float s = e0 + e1;
    #pragma unroll
    for (int off = 32; off; off >>= 1) s += __shfl_xor(s, off);
    if (lane == 0) reds[wv] = s;
    __syncthreads();
    s = reds[0] + reds[1] + reds[2] + reds[3];
    float inv = 1.f / s;

    att[(size_t)bi * N + tid]       = e0 * inv;
    att[(size_t)bi * N + tid + 256] = e1 * inv;
}

// ---------------------------------------------------------------------------
// K3: out = elu(att @ h).  8 rows per block, att tile in LDS, h from L2.
// ---------------------------------------------------------------------------
__global__ __launch_bounds__(256) void k_out(const float* __restrict__ att,
                                             const float* __restrict__ h,
                                             float* __restrict__ out) {
    constexpr int ROWS = 8;
    int row0 = blockIdx.x * ROWS;       // over B*N
    int b = row0 >> 9;
    int o = threadIdx.x;
    __shared__ float as_[ROWS][N];      // 16 KB
    #pragma unroll
    for (int r = 0; r < ROWS; ++r) {
        as_[r][o]       = att[(size_t)(row0 + r) * N + o];
        as_[r][o + 256] = att[(size_t)(row0 + r) * N + o + 256];
    }
    __syncthreads();

    float acc[ROWS];
    #pragma unroll
    for (int r = 0; r < ROWS; ++r) acc[r] = 0.f;

    const float* hb = h + (size_t)b * N * OUT_F;
    for (int k = 0; k < N; k += 4) {
        float h0 = hb[(size_t)(k + 0) * OUT_F + o];
        float h1 = hb[(size_t)(k + 1) * OUT_F + o];
        float h2 = hb[(size_t)(k + 2) * OUT_F + o];
        float h3 = hb[(size_t)(k + 3) * OUT_F + o];
        #pragma unroll
        for (int r = 0; r < ROWS; ++r) {
            float4 av = *(const float4*)&as_[r][k];
            acc[r] = fmaf(av.x, h0, acc[r]);
            acc[r] = fmaf(av.y, h1, acc[r]);
            acc[r] = fmaf(av.z, h2, acc[r]);
            acc[r] = fmaf(av.w, h3, acc[r]);
        }
    }
    #pragma unroll
    for (int r = 0; r < ROWS; ++r) {
        float v = acc[r];
        out[(size_t)(row0 + r) * OUT_F + o] = v > 0.f ? v : (expf(v) - 1.f);
    }
}

// ---------------------------------------------------------------------------
extern "C" void kernel_launch(void* const* d_in, const int* in_sizes, int n_in,
                              void* d_out, int out_size, void* d_ws, size_t ws_size,
                              hipStream_t stream) {
    const float* x    = (const float*)d_in[0];   // (4,512,256)
    const float* edge = (const float*)d_in[1];   // (4,512,512,64)
    const float* adj  = (const float*)d_in[2];   // (4,512,512)
    const float* W    = (const float*)d_in[3];   // (256,256)
    const float* W1   = (const float*)d_in[4];   // (64,256)
    const float* a    = (const float*)d_in[5];   // (768,1)
    float* out = (float*)d_out;                  // (4,512,256)

    float* ws = (float*)d_ws;
    float* h_buf   = ws;                                  // 4*512*256   = 524288
    float* att_buf = h_buf + (size_t)B * N * OUT_F;       // 4*512*512   = 1048576
    float* si_buf  = att_buf + (size_t)B * N * N;         // 2048
    float* sj_buf  = si_buf + B * N;                      // 2048
    float* w1a3_buf = sj_buf + B * N;                     // 64

    k_w1a3<<<1, 256, 0, stream>>>(W1, a, w1a3_buf);
    k_h<<<(B * N) / 8, 256, 0, stream>>>(x, W, a, h_buf, si_buf, sj_buf);
    k_att<<<B * N, 256, 0, stream>>>(edge, adj, si_buf, sj_buf, w1a3_buf, att_buf);
    k_out<<<(B * N) / 8, 256, 0, stream>>>(att_buf, h_buf, out);
}